// Round 1
// baseline (1023.491 us; speedup 1.0000x reference)
//
#include <hip/hip_runtime.h>
#include <cmath>

// Problem constants: B=16, N=1024, D=512, HEAD=256.  BN = 16384 rows.
#define BN   16384
#define DD   512
#define HEADN 256

// ---------------------------------------------------------------------------
// Generic fp32 GEMM: Cout = epi( A(MxK) @ W(KxN) [+ Cin] , bias, denom )
//   epi 0: acc (+ bias[c] if bias)          -> store
//   epi 1: tanh(acc + bias[c])              -> store
//   epi 2: relu((acc + 2*bias[c])/denom[r]) -> store
// Tile 64x64, K-step 16, 256 threads, 4x4 micro-tile per thread.
// M,N,K all multiples of 64/16 (hard-coded shapes satisfy this).
// ---------------------------------------------------------------------------
__global__ __launch_bounds__(256) void gemm_fp32(
    const float* __restrict__ A, const float* __restrict__ W,
    const float* __restrict__ bias, const float* __restrict__ Cin,
    float* __restrict__ Cout, const float* __restrict__ denom,
    int M, int N, int K, int epi)
{
    __shared__ float As[16][68];
    __shared__ float Bs[16][68];

    const int nb = N >> 6;
    const int bx = blockIdx.x % nb;
    const int by = blockIdx.x / nb;
    const int t  = threadIdx.x;
    const int tx = t & 15, ty = t >> 4;
    const int row0 = ty << 2, col0 = tx << 2;
    const int m0 = by << 6, n0 = bx << 6;

    // staging indices
    const int am = t >> 2;          // 0..63 (A tile row)
    const int ak = (t & 3) << 2;    // 0,4,8,12 (A tile k)
    const int bk = t >> 4;          // 0..15 (B tile k)
    const int bn = (t & 15) << 2;   // 0..60 (B tile col)

    float acc[4][4] = {};

    for (int k0 = 0; k0 < K; k0 += 16) {
        float4 av4 = *(const float4*)(A + (size_t)(m0 + am) * K + k0 + ak);
        float4 bv4 = *(const float4*)(W + (size_t)(k0 + bk) * N + n0 + bn);
        __syncthreads();
        As[ak + 0][am] = av4.x;
        As[ak + 1][am] = av4.y;
        As[ak + 2][am] = av4.z;
        As[ak + 3][am] = av4.w;
        *(float4*)&Bs[bk][bn] = bv4;
        __syncthreads();
#pragma unroll
        for (int kk = 0; kk < 16; ++kk) {
            float4 a4 = *(const float4*)&As[kk][row0];
            float4 b4 = *(const float4*)&Bs[kk][col0];
            float ar[4] = {a4.x, a4.y, a4.z, a4.w};
            float br[4] = {b4.x, b4.y, b4.z, b4.w};
#pragma unroll
            for (int i = 0; i < 4; ++i)
#pragma unroll
                for (int j = 0; j < 4; ++j)
                    acc[i][j] = fmaf(ar[i], br[j], acc[i][j]);
        }
    }

#pragma unroll
    for (int i = 0; i < 4; ++i) {
        const int gr = m0 + row0 + i;
        const size_t off = (size_t)gr * N + n0 + col0;
        float v[4] = {acc[i][0], acc[i][1], acc[i][2], acc[i][3]};
        if (Cin) {
            float4 cv = *(const float4*)(Cin + off);
            v[0] += cv.x; v[1] += cv.y; v[2] += cv.z; v[3] += cv.w;
        }
        if (epi == 1) {
#pragma unroll
            for (int j = 0; j < 4; ++j) v[j] = tanhf(v[j] + bias[n0 + col0 + j]);
        } else if (epi == 2) {
            const float dv = denom[gr];
#pragma unroll
            for (int j = 0; j < 4; ++j) {
                float u = (v[j] + 2.0f * bias[n0 + col0 + j]) / dv;
                v[j] = u > 0.0f ? u : 0.0f;
            }
        } else if (bias) {
#pragma unroll
            for (int j = 0; j < 4; ++j) v[j] += bias[n0 + col0 + j];
        }
        float4 outv = {v[0], v[1], v[2], v[3]};
        *(float4*)(Cout + off) = outv;
    }
}

// ---------------------------------------------------------------------------
// Per-row: s = dot(U[r], tc[r]); fdot = dot(x[r], fi_w); a=exp(s), f=exp(fdot);
// atomic per-batch S += a, H += a*f.  One wave per row.
// ---------------------------------------------------------------------------
__global__ __launch_bounds__(256) void rowdots_kernel(
    const float* __restrict__ U, const float* __restrict__ tc,
    const float* __restrict__ x, const float* __restrict__ fiw,
    float* __restrict__ a_out, float* __restrict__ f_out,
    float* __restrict__ Sb, float* __restrict__ Hb)
{
    const int wave = threadIdx.x >> 6;
    const int lane = threadIdx.x & 63;
    const int r = (blockIdx.x << 2) + wave;
    const float* Ur  = U  + (size_t)r * DD;
    const float* tcr = tc + (size_t)r * DD;
    const float* xr  = x  + (size_t)r * DD;
    float su = 0.0f, sf = 0.0f;
#pragma unroll
    for (int j = 0; j < DD / 64; ++j) {
        int c = lane + (j << 6);
        su = fmaf(Ur[c], tcr[c], su);
        sf = fmaf(xr[c], fiw[c], sf);
    }
#pragma unroll
    for (int off = 32; off > 0; off >>= 1) {
        su += __shfl_xor(su, off);
        sf += __shfl_xor(sf, off);
    }
    if (lane == 0) {
        float av = expf(su), fv = expf(sf);
        a_out[r] = av;
        f_out[r] = fv;
        int b = r >> 10;
        atomicAdd(&Sb[b], av);
        atomicAdd(&Hb[b], av * fv);
    }
}

// denom[r] = 2 - a[r]*f[r]/H[b]
__global__ void prep_row_kernel(const float* __restrict__ a, const float* __restrict__ f,
                                const float* __restrict__ Hb, float* __restrict__ denom)
{
    int r = blockIdx.x * 256 + threadIdx.x;
    denom[r] = 2.0f - a[r] * f[r] / Hb[r >> 10];
}

// Per batch b: P[c] = sum_n a_n V[n,c]; Q[c] = sum_n a_n f_n V[n,c]
// grid = 16 batches * 8 row-chunks; atomicAdd partials.
__global__ __launch_bounds__(256) void batch_pq_kernel(
    const float* __restrict__ V, const float* __restrict__ a, const float* __restrict__ f,
    float* __restrict__ P, float* __restrict__ Q, int C)
{
    const int b = blockIdx.x >> 3;
    const int chunk = blockIdx.x & 7;
    const float* Vb = V + (size_t)b * 1024 * C;
    const float* ab = a + (b << 10);
    const float* fb = f + (b << 10);
    const int n0 = chunk << 7;
    for (int c = threadIdx.x; c < C; c += 256) {
        float p = 0.0f, q = 0.0f;
        for (int n = n0; n < n0 + 128; ++n) {
            float av = ab[n];
            float xv = Vb[(size_t)n * C + c];
            p = fmaf(av, xv, p);
            q = fmaf(av * fb[n], xv, q);
        }
        atomicAdd(&P[b * C + c], p);
        atomicAdd(&Q[b * C + c], q);
    }
}

// h[r,c] = (1 - a/S)*V[r,c] + (1/S - (a/(S*H))*f)*P[c] + (a/(S*H))*Q[c]
//        = adj@V + V  (rank-3 + diagonal closed form)
__global__ void mix_kernel(const float* __restrict__ V, const float* __restrict__ P,
                           const float* __restrict__ Q, const float* __restrict__ a,
                           const float* __restrict__ f, const float* __restrict__ Sb,
                           const float* __restrict__ Hb, float* __restrict__ out, int C)
{
    int idx = blockIdx.x * 256 + threadIdx.x;
    int r = idx / C, c = idx - r * C;
    int b = r >> 10;
    float av = a[r], fv = f[r], S = Sb[b], H = Hb[b];
    float beta = av / (S * H);
    float alpha = 1.0f - av / S;
    float coefP = 1.0f / S - beta * fv;
    out[idx] = alpha * V[idx] + coefP * P[b * C + c] + beta * Q[b * C + c];
}

// gcn[r,c] = (c<256 ? g0[r,c] : g1[r,c-256]) + x[r,c]
__global__ void concat_kernel(const float* __restrict__ g0, const float* __restrict__ g1,
                              const float* __restrict__ x, float* __restrict__ out)
{
    int idx = blockIdx.x * 256 + threadIdx.x;
    int r = idx >> 9, c = idx & 511;
    float g = (c < HEADN) ? g0[(size_t)r * HEADN + c] : g1[(size_t)r * HEADN + c - HEADN];
    out[idx] = g + x[idx];
}

extern "C" void kernel_launch(void* const* d_in, const int* in_sizes, int n_in,
                              void* d_out, int out_size, void* d_ws, size_t ws_size,
                              hipStream_t stream)
{
    (void)in_sizes; (void)n_in; (void)out_size; (void)ws_size;
    const float* x    = (const float*)d_in[0];
    const float* tp_w = (const float*)d_in[1];
    const float* tp_b = (const float*)d_in[2];
    const float* tc_w = (const float*)d_in[3];
    const float* tc_b = (const float*)d_in[4];
    const float* fi_w = (const float*)d_in[5];
    const float* bilw = (const float*)d_in[6];
    const float* w0   = (const float*)d_in[7];
    const float* b0   = (const float*)d_in[8];
    const float* w1   = (const float*)d_in[9];
    const float* b1   = (const float*)d_in[10];
    const float* ow   = (const float*)d_in[11];
    const float* ob   = (const float*)d_in[12];
    float* out = (float*)d_out;

    float* ws = (float*)d_ws;
    float* bufA  = ws;                       // 8.4M floats: tp -> h0 -> gcn
    float* bufB  = ws + 8388608;             // 8.4M floats: tc -> hg
    float* bufG0 = ws + 16777216;            // 4.2M floats: g0
    float* bufT  = bufG0 + 4194304;          // 4.2M floats: T -> g1
    float* bufU  = bufG0;                    // 8.4M floats (spans G0+T while live)
    float* arr_a   = ws + 25165824;          // 16384
    float* arr_f   = arr_a + BN;             // 16384
    float* arr_den = arr_f + BN;             // 16384
    float* stats   = arr_den + BN;           // S(16) H(16) P0(8192) Q0(8192) P1(4096) Q1(4096)
    float* Sb = stats;
    float* Hb = stats + 16;
    float* P0 = Hb + 16;
    float* Q0 = P0 + 16 * DD;
    float* P1 = Q0 + 16 * DD;
    float* Q1 = P1 + 16 * HEADN;

    hipMemsetAsync(stats, 0, (size_t)(32 + 2 * 16 * DD + 2 * 16 * HEADN) * sizeof(float), stream);

    // 1) tp = tanh(x@tp_w + tp_b); tc = tanh(x@tc_w + tc_b)
    gemm_fp32<<<2048, 256, 0, stream>>>(x, tp_w, tp_b, nullptr, bufA, nullptr, BN, DD, DD, 1);
    gemm_fp32<<<2048, 256, 0, stream>>>(x, tc_w, tc_b, nullptr, bufB, nullptr, BN, DD, DD, 1);
    // 2) U = tp @ bil_w
    gemm_fp32<<<2048, 256, 0, stream>>>(bufA, bilw, nullptr, nullptr, bufU, nullptr, BN, DD, DD, 0);
    // 3) a = exp(s), f = exp(x@fi_w), batch S/H
    rowdots_kernel<<<4096, 256, 0, stream>>>(bufU, bufB, x, fi_w, arr_a, arr_f, Sb, Hb);
    // 4) denom[r] = 2 - a*f/H
    prep_row_kernel<<<64, 256, 0, stream>>>(arr_a, arr_f, Hb, arr_den);
    // 5) layer-0: P0,Q0 over x; h0 = adj@x + x
    batch_pq_kernel<<<128, 256, 0, stream>>>(x, arr_a, arr_f, P0, Q0, DD);
    mix_kernel<<<32768, 256, 0, stream>>>(x, P0, Q0, arr_a, arr_f, Sb, Hb, bufA, DD);
    // 6) g0 = relu((h0@W0 + 2*b0)/denom)
    gemm_fp32<<<1024, 256, 0, stream>>>(bufA, w0, b0, nullptr, bufG0, arr_den, BN, HEADN, DD, 2);
    // 7) layer-1: P1,Q1 over g0; hg = adj@g0 + g0
    batch_pq_kernel<<<128, 256, 0, stream>>>(bufG0, arr_a, arr_f, P1, Q1, HEADN);
    mix_kernel<<<16384, 256, 0, stream>>>(bufG0, P1, Q1, arr_a, arr_f, Sb, Hb, bufB, HEADN);
    // 8) g1 = relu((h0@W1top + hg@W1bot + 2*b1)/denom)
    gemm_fp32<<<1024, 256, 0, stream>>>(bufA, w1, nullptr, nullptr, bufT, nullptr, BN, HEADN, DD, 0);
    gemm_fp32<<<1024, 256, 0, stream>>>(bufB, w1 + 512 * 256, b1, bufT, bufT, arr_den, BN, HEADN, HEADN, 2);
    // 9) gcn = [g0,g1] + x ; out = gcn@out_w + out_b
    concat_kernel<<<32768, 256, 0, stream>>>(bufG0, bufT, x, bufA);
    gemm_fp32<<<2048, 256, 0, stream>>>(bufA, ow, ob, nullptr, out, nullptr, BN, DD, DD, 0);
}

// Round 2
// 334.163 us; speedup vs baseline: 3.0628x; 3.0628x over previous
//
#include <hip/hip_runtime.h>
#include <cmath>

// B=16, N=1024, D=512, HEAD=256.  BN = 16384 rows.
#define BN   16384
#define DD   512
#define HEADN 256

typedef unsigned short ushort;
typedef short short8 __attribute__((ext_vector_type(8)));
typedef float floatx4 __attribute__((ext_vector_type(4)));
typedef unsigned short ushort4v __attribute__((ext_vector_type(4)));
typedef unsigned short ushort8v __attribute__((ext_vector_type(8)));

__device__ __forceinline__ ushort f2bf(float v) {
    unsigned int u = __float_as_uint(v);
    unsigned int r = u + 0x7FFFu + ((u >> 16) & 1u);
    return (ushort)(r >> 16);
}
__device__ __forceinline__ float bf2f(ushort u) {
    return __uint_as_float(((unsigned int)u) << 16);
}

// ---------------------------------------------------------------------------
// bf16 MFMA GEMM: C(MxN) = epi( A(M x lda, uses K cols) @ Bt(N x K)^T )
//  epi 0: fp32 store acc + bias[c]
//  epi 1: bf16 store tanh(acc + bias[c])
//  epi 2: fp32 store relu((acc + 2*bias[c]) / denom[r])
//  epi 3: no store; s_arr[r] += sum_c acc[r][c]*tc[r][c]   (tc row stride 512)
// Tile 128x128, BK=32, 256 threads = 4 waves (each 64x64 via 4x4 MFMA tiles).
// LDS staged via global_load_lds width=16 with XOR chunk swizzle
// slot(row,c) = c ^ ((row>>1)&3)  -> frag ds_read_b128 is 2-way max (free).
// ---------------------------------------------------------------------------
__global__ __launch_bounds__(256) void gemm_bf16(
    const ushort* __restrict__ A, int lda,
    const ushort* __restrict__ Bt, int N, int K,
    const float* __restrict__ bias,
    const float* __restrict__ denom,
    const ushort* __restrict__ tcb,
    float* __restrict__ s_arr,
    void* __restrict__ Cout, int epi)
{
    __shared__ ushort As[128 * 32];
    __shared__ ushort Bs[128 * 32];

    const int nb = N >> 7;
    const int bx = blockIdx.x % nb;
    const int by = blockIdx.x / nb;
    const int m0 = by << 7, n0 = bx << 7;
    const int tid = threadIdx.x;
    const int w = tid >> 6, L = tid & 63;
    const int wr0 = (w >> 1) << 6, wc0 = (w & 1) << 6;
    const int lrow = L & 15, quad = L >> 4;
    const int srow = L >> 2, sslot = L & 3;   // staging: 4 lanes per row

    floatx4 zero4 = {0.0f, 0.0f, 0.0f, 0.0f};
    floatx4 acc[4][4];
#pragma unroll
    for (int i = 0; i < 4; ++i)
#pragma unroll
        for (int j = 0; j < 4; ++j) acc[i][j] = zero4;

    for (int k0 = 0; k0 < K; k0 += 32) {
        __syncthreads();
#pragma unroll
        for (int i = 0; i < 2; ++i) {
            const int rl = (w << 5) + (i << 4) + srow;         // tile row 0..127
            const int ca = sslot ^ ((rl >> 1) & 3);            // chunk to fetch
            const ushort* ga = A + (size_t)(m0 + rl) * lda + k0 + (ca << 3);
            __builtin_amdgcn_global_load_lds(
                (const __attribute__((address_space(1))) unsigned int*)ga,
                (__attribute__((address_space(3))) unsigned int*)(As + ((w << 5) + (i << 4)) * 32),
                16, 0, 0);
            const ushort* gb = Bt + (size_t)(n0 + rl) * K + k0 + (ca << 3);
            __builtin_amdgcn_global_load_lds(
                (const __attribute__((address_space(1))) unsigned int*)gb,
                (__attribute__((address_space(3))) unsigned int*)(Bs + ((w << 5) + (i << 4)) * 32),
                16, 0, 0);
        }
        __syncthreads();

        short8 af[4], bfr[4];
#pragma unroll
        for (int mi = 0; mi < 4; ++mi) {
            const int row = wr0 + (mi << 4) + lrow;
            const int slot = quad ^ ((row >> 1) & 3);
            af[mi] = *(const short8*)(As + row * 32 + (slot << 3));
        }
#pragma unroll
        for (int ni = 0; ni < 4; ++ni) {
            const int row = wc0 + (ni << 4) + lrow;
            const int slot = quad ^ ((row >> 1) & 3);
            bfr[ni] = *(const short8*)(Bs + row * 32 + (slot << 3));
        }
#pragma unroll
        for (int mi = 0; mi < 4; ++mi)
#pragma unroll
            for (int ni = 0; ni < 4; ++ni)
                acc[mi][ni] = __builtin_amdgcn_mfma_f32_16x16x32_bf16(
                    af[mi], bfr[ni], acc[mi][ni], 0, 0, 0);
    }

    // C/D layout (m89-verified): col = lane&15, row = (lane>>4)*4 + reg.
    if (epi == 3) {
#pragma unroll
        for (int mi = 0; mi < 4; ++mi) {
            float rs[4] = {0.f, 0.f, 0.f, 0.f};
#pragma unroll
            for (int ni = 0; ni < 4; ++ni) {
                const int gc = n0 + wc0 + (ni << 4) + lrow;
#pragma unroll
                for (int p = 0; p < 4; ++p) {
                    const int gr = m0 + wr0 + (mi << 4) + (quad << 2) + p;
                    rs[p] += acc[mi][ni][p] * bf2f(tcb[(size_t)gr * 512 + gc]);
                }
            }
#pragma unroll
            for (int p = 0; p < 4; ++p)
#pragma unroll
                for (int o = 1; o < 16; o <<= 1) rs[p] += __shfl_xor(rs[p], o);
            if (lrow == 0) {
#pragma unroll
                for (int p = 0; p < 4; ++p)
                    atomicAdd(s_arr + m0 + wr0 + (mi << 4) + (quad << 2) + p, rs[p]);
            }
        }
    } else {
#pragma unroll
        for (int mi = 0; mi < 4; ++mi) {
#pragma unroll
            for (int p = 0; p < 4; ++p) {
                const int gr = m0 + wr0 + (mi << 4) + (quad << 2) + p;
                const float dv = (epi == 2) ? denom[gr] : 1.0f;
#pragma unroll
                for (int ni = 0; ni < 4; ++ni) {
                    const int gc = n0 + wc0 + (ni << 4) + lrow;
                    const float v = acc[mi][ni][p];
                    if (epi == 0) {
                        ((float*)Cout)[(size_t)gr * N + gc] = v + bias[gc];
                    } else if (epi == 1) {
                        ((ushort*)Cout)[(size_t)gr * N + gc] = f2bf(tanhf(v + bias[gc]));
                    } else {
                        float u = (v + 2.0f * bias[gc]) / dv;
                        ((float*)Cout)[(size_t)gr * N + gc] = u > 0.0f ? u : 0.0f;
                    }
                }
            }
        }
    }
}

// ---------------------------------------------------------------------------
// Weight transpose+convert: W[K][N] fp32 -> Wt[N][K] bf16. 32x32 LDS tiles.
// ---------------------------------------------------------------------------
__global__ __launch_bounds__(256) void transpose_w(
    const float* __restrict__ W, ushort* __restrict__ Wt, int K, int N)
{
    __shared__ float t[32][33];
    const int nb = N >> 5;
    const int kb = blockIdx.x / nb, nbb = blockIdx.x % nb;
    const int k0 = kb << 5, n0 = nbb << 5;
    const int c = threadIdx.x & 31, r = threadIdx.x >> 5;   // r 0..7
#pragma unroll
    for (int i = 0; i < 4; ++i)
        t[r + 8 * i][c] = W[(size_t)(k0 + r + 8 * i) * N + n0 + c];
    __syncthreads();
#pragma unroll
    for (int i = 0; i < 4; ++i)
        Wt[(size_t)(n0 + r + 8 * i) * K + k0 + c] = f2bf(t[c][r + 8 * i]);
}

// ---------------------------------------------------------------------------
// Fused: xb = bf16(x)  and  fdot[r] = x[r] . fiw.  One wave per row.
// ---------------------------------------------------------------------------
__global__ __launch_bounds__(256) void convx_fdot(
    const float* __restrict__ x, const float* __restrict__ fiw,
    ushort* __restrict__ xb, float* __restrict__ fdot)
{
    const int w = threadIdx.x >> 6, L = threadIdx.x & 63;
    const int r = (blockIdx.x << 2) + w;
    const float* xr = x + (size_t)r * DD;
    const int c0 = L << 3;
    float4 v0 = *(const float4*)(xr + c0);
    float4 v1 = *(const float4*)(xr + c0 + 4);
    float4 f0 = *(const float4*)(fiw + c0);
    float4 f1 = *(const float4*)(fiw + c0 + 4);
    float d = v0.x * f0.x + v0.y * f0.y + v0.z * f0.z + v0.w * f0.w
            + v1.x * f1.x + v1.y * f1.y + v1.z * f1.z + v1.w * f1.w;
    ushort8v o;
    o[0] = f2bf(v0.x); o[1] = f2bf(v0.y); o[2] = f2bf(v0.z); o[3] = f2bf(v0.w);
    o[4] = f2bf(v1.x); o[5] = f2bf(v1.y); o[6] = f2bf(v1.z); o[7] = f2bf(v1.w);
    *(ushort8v*)(xb + (size_t)r * DD + c0) = o;
#pragma unroll
    for (int off = 32; off > 0; off >>= 1) d += __shfl_xor(d, off);
    if (L == 0) fdot[r] = d;
}

// ---------------------------------------------------------------------------
// Per batch (block = 1024 threads = 1 batch): a=exp(s), f=exp(fdot),
// S=sum a, H=sum a*f (tree reduce, NO atomics), denom = 2 - a*f/H.
// ---------------------------------------------------------------------------
__global__ __launch_bounds__(1024) void finalize_k(
    const float* __restrict__ s_arr, const float* __restrict__ fdot,
    float* __restrict__ a, float* __restrict__ f,
    float* __restrict__ Sb, float* __restrict__ Hb, float* __restrict__ den)
{
    __shared__ float redS[16], redH[16];
    __shared__ float Hsh;
    const int b = blockIdx.x, t = threadIdx.x;
    const int r = (b << 10) + t;
    const float av = expf(s_arr[r]), fv = expf(fdot[r]);
    a[r] = av; f[r] = fv;
    float s1 = av, s2 = av * fv;
#pragma unroll
    for (int o = 32; o > 0; o >>= 1) { s1 += __shfl_xor(s1, o); s2 += __shfl_xor(s2, o); }
    if ((t & 63) == 0) { redS[t >> 6] = s1; redH[t >> 6] = s2; }
    __syncthreads();
    if (t == 0) {
        float S = 0.f, H = 0.f;
        for (int i = 0; i < 16; ++i) { S += redS[i]; H += redH[i]; }
        Sb[b] = S; Hb[b] = H; Hsh = H;
    }
    __syncthreads();
    den[r] = 2.0f - av * fv / Hsh;
}

// ---------------------------------------------------------------------------
// Per batch: P[c] = sum_n a_n V[n,c]; Q[c] = sum_n a_n f_n V[n,c].
// grid = 16 batches x 16 row-chunks(64); LDS-reduce then <=16-collider atomics.
// ---------------------------------------------------------------------------
__global__ __launch_bounds__(256) void batch_pq(
    const float* __restrict__ V, const float* __restrict__ a, const float* __restrict__ f,
    float* __restrict__ P, float* __restrict__ Q, int C)
{
    __shared__ float redP[256][4];
    __shared__ float redQ[256][4];
    const int b = blockIdx.x >> 4;
    const int chunk = blockIdx.x & 15;
    const int c4cnt = C >> 2;
    const int rg = 256 / c4cnt;
    const int c4 = threadIdx.x & (c4cnt - 1);
    const int sub = threadIdx.x / c4cnt;
    const float* Vb = V + (size_t)b * 1024 * C;
    const float* ab = a + (b << 10);
    const float* fb = f + (b << 10);
    const int n0 = chunk << 6;
    float4 p = {0, 0, 0, 0}, q = {0, 0, 0, 0};
    for (int n = n0 + sub; n < n0 + 64; n += rg) {
        const float av = ab[n], afv = av * fb[n];
        const float4 v = *(const float4*)(Vb + (size_t)n * C + (c4 << 2));
        p.x += av * v.x; p.y += av * v.y; p.z += av * v.z; p.w += av * v.w;
        q.x += afv * v.x; q.y += afv * v.y; q.z += afv * v.z; q.w += afv * v.w;
    }
    redP[threadIdx.x][0] = p.x; redP[threadIdx.x][1] = p.y;
    redP[threadIdx.x][2] = p.z; redP[threadIdx.x][3] = p.w;
    redQ[threadIdx.x][0] = q.x; redQ[threadIdx.x][1] = q.y;
    redQ[threadIdx.x][2] = q.z; redQ[threadIdx.x][3] = q.w;
    __syncthreads();
    if (sub == 0) {
        for (int s = 1; s < rg; ++s) {
            const int t2 = threadIdx.x + s * c4cnt;
            p.x += redP[t2][0]; p.y += redP[t2][1]; p.z += redP[t2][2]; p.w += redP[t2][3];
            q.x += redQ[t2][0]; q.y += redQ[t2][1]; q.z += redQ[t2][2]; q.w += redQ[t2][3];
        }
        float* Pp = P + b * C + (c4 << 2);
        float* Qp = Q + b * C + (c4 << 2);
        atomicAdd(Pp + 0, p.x); atomicAdd(Pp + 1, p.y);
        atomicAdd(Pp + 2, p.z); atomicAdd(Pp + 3, p.w);
        atomicAdd(Qp + 0, q.x); atomicAdd(Qp + 1, q.y);
        atomicAdd(Qp + 2, q.z); atomicAdd(Qp + 3, q.w);
    }
}

// ---------------------------------------------------------------------------
// h = adj@V + V (rank-3 + diagonal closed form), store bf16 into
// outb[r][co .. co+C) with row stride ldo.
// ---------------------------------------------------------------------------
__global__ __launch_bounds__(256) void mix_k(
    const float* __restrict__ V, const float* __restrict__ P, const float* __restrict__ Q,
    const float* __restrict__ a, const float* __restrict__ f,
    const float* __restrict__ Sb, const float* __restrict__ Hb,
    ushort* __restrict__ outb, int C, int ldo, int co)
{
    const int idx = blockIdx.x * 256 + threadIdx.x;
    const int c4c = C >> 2;
    const int r = idx / c4c, c4 = idx - r * c4c;
    const int b = r >> 10;
    const float av = a[r], fv = f[r], S = Sb[b], H = Hb[b];
    const float beta = av / (S * H);
    const float alpha = 1.0f - av / S;
    const float cp = 1.0f / S - beta * fv;
    const float4 v = *(const float4*)(V + (size_t)r * C + (c4 << 2));
    const float* Pp = P + b * C + (c4 << 2);
    const float* Qp = Q + b * C + (c4 << 2);
    ushort4v o;
    o[0] = f2bf(alpha * v.x + cp * Pp[0] + beta * Qp[0]);
    o[1] = f2bf(alpha * v.y + cp * Pp[1] + beta * Qp[1]);
    o[2] = f2bf(alpha * v.z + cp * Pp[2] + beta * Qp[2]);
    o[3] = f2bf(alpha * v.w + cp * Pp[3] + beta * Qp[3]);
    *(ushort4v*)(outb + (size_t)r * ldo + co + (c4 << 2)) = o;
}

// gcnb[r][c] = bf16( (c<256 ? g0 : g1)[r][c%256] + x[r][c] )
__global__ __launch_bounds__(256) void concat_k(
    const float* __restrict__ g0, const float* __restrict__ g1,
    const float* __restrict__ x, ushort* __restrict__ gcnb)
{
    const int idx = blockIdx.x * 256 + threadIdx.x;   // over BN*128
    const int r = idx >> 7, c4 = idx & 127;
    const int c = c4 << 2;
    const float4 g = (c < HEADN)
        ? *(const float4*)(g0 + (size_t)r * HEADN + c)
        : *(const float4*)(g1 + (size_t)r * HEADN + c - HEADN);
    const float4 xv = *(const float4*)(x + (size_t)r * DD + c);
    ushort4v o;
    o[0] = f2bf(g.x + xv.x); o[1] = f2bf(g.y + xv.y);
    o[2] = f2bf(g.z + xv.z); o[3] = f2bf(g.w + xv.w);
    *(ushort4v*)(gcnb + (size_t)r * DD + c) = o;
}

extern "C" void kernel_launch(void* const* d_in, const int* in_sizes, int n_in,
                              void* d_out, int out_size, void* d_ws, size_t ws_size,
                              hipStream_t stream)
{
    (void)in_sizes; (void)n_in; (void)out_size; (void)ws_size;
    const float* x    = (const float*)d_in[0];
    const float* tp_w = (const float*)d_in[1];
    const float* tp_b = (const float*)d_in[2];
    const float* tc_w = (const float*)d_in[3];
    const float* tc_b = (const float*)d_in[4];
    const float* fi_w = (const float*)d_in[5];
    const float* bilw = (const float*)d_in[6];
    const float* w0   = (const float*)d_in[7];
    const float* b0   = (const float*)d_in[8];
    const float* w1   = (const float*)d_in[9];
    const float* b1   = (const float*)d_in[10];
    const float* ow   = (const float*)d_in[11];
    const float* ob   = (const float*)d_in[12];

    char* W = (char*)d_ws;
    ushort* xb   = (ushort*)(W);                         // [0,16M)  -> reused as gcnb
    ushort* gcnb = xb;
    ushort* tpb  = (ushort*)(W + ((size_t)16 << 20));    // [16M,32M)
    ushort* tcb  = (ushort*)(W + ((size_t)32 << 20));    // [32M,48M)
    ushort* Abig = tpb;                                  // 24M, overlays tpb+tcb (both dead)
    float*  g0   = (float*)(W + ((size_t)48 << 20));
    float*  g1   = (float*)(W + ((size_t)64 << 20));
    ushort* tpwT = (ushort*)(W + ((size_t)80 << 20));
    ushort* tcwT = tpwT + 262144;
    ushort* bilwT= tcwT + 262144;
    ushort* w0T  = bilwT + 262144;     // 256x512
    ushort* w1T  = w0T + 131072;       // 256x768
    ushort* owT  = w1T + 196608;       // 512x512
    float* stats = (float*)(W + ((size_t)84 << 20));
    float* s_arr = stats;              // 16384  (memset)
    float* P0    = s_arr + 16384;      // 8192   (memset)
    float* Q0    = P0 + 8192;          // 8192   (memset)
    float* P1    = Q0 + 8192;          // 4096   (memset)
    float* Q1    = P1 + 4096;          // 4096   (memset)
    float* fdot  = Q1 + 4096;
    float* arr_a = fdot + BN;
    float* arr_f = arr_a + BN;
    float* arr_den = arr_f + BN;
    float* Sb    = arr_den + BN;
    float* Hb    = Sb + 16;

    hipMemsetAsync(s_arr, 0, (16384 + 2 * 8192 + 2 * 4096) * sizeof(float), stream);

    // x -> bf16 + f-dot
    convx_fdot<<<4096, 256, 0, stream>>>(x, fi_w, xb, fdot);
    // weight transposes (fp32 -> bf16 [N][K])
    transpose_w<<<256, 256, 0, stream>>>(tp_w, tpwT, 512, 512);
    transpose_w<<<256, 256, 0, stream>>>(tc_w, tcwT, 512, 512);
    transpose_w<<<256, 256, 0, stream>>>(bilw, bilwT, 512, 512);
    transpose_w<<<128, 256, 0, stream>>>(w0, w0T, 512, 256);
    transpose_w<<<192, 256, 0, stream>>>(w1, w1T, 768, 256);
    transpose_w<<<256, 256, 0, stream>>>(ow, owT, 512, 512);
    // tp = tanh(x@tp_w+b) (bf16 out), tc likewise
    gemm_bf16<<<512, 256, 0, stream>>>(xb, 512, tpwT, 512, 512, tp_b, nullptr, nullptr, nullptr, tpb, 1);
    gemm_bf16<<<512, 256, 0, stream>>>(xb, 512, tcwT, 512, 512, tc_b, nullptr, nullptr, nullptr, tcb, 1);
    // s[r] = (tp@bilw)[r] . tc[r]   (U never materialized)
    gemm_bf16<<<512, 256, 0, stream>>>(tpb, 512, bilwT, 512, 512, nullptr, nullptr, tcb, s_arr, nullptr, 3);
    // a, f, S, H, denom
    finalize_k<<<16, 1024, 0, stream>>>(s_arr, fdot, arr_a, arr_f, Sb, Hb, arr_den);
    // layer 0: h0 = adj@x + x -> Abig[:, 0:512] bf16
    batch_pq<<<256, 256, 0, stream>>>(x, arr_a, arr_f, P0, Q0, 512);
    mix_k<<<8192, 256, 0, stream>>>(x, P0, Q0, arr_a, arr_f, Sb, Hb, Abig, 512, 768, 0);
    // g0 = relu((h0@W0 + 2 b0)/denom)  fp32
    gemm_bf16<<<256, 256, 0, stream>>>(Abig, 768, w0T, 256, 512, b0, arr_den, nullptr, nullptr, g0, 2);
    // layer 1: hg = adj@g0 + g0 -> Abig[:, 512:768] bf16
    batch_pq<<<256, 256, 0, stream>>>(g0, arr_a, arr_f, P1, Q1, 256);
    mix_k<<<4096, 256, 0, stream>>>(g0, P1, Q1, arr_a, arr_f, Sb, Hb, Abig, 256, 768, 512);
    // g1 = relu(([h0|hg]@W1 + 2 b1)/denom)  fp32   (fused K=768)
    gemm_bf16<<<256, 256, 0, stream>>>(Abig, 768, w1T, 256, 768, b1, arr_den, nullptr, nullptr, g1, 2);
    // gcn = [g0|g1] + x  (bf16) ; out = gcn@out_w + out_b (fp32)
    concat_k<<<8192, 256, 0, stream>>>(g0, g1, x, gcnb);
    gemm_bf16<<<512, 256, 0, stream>>>(gcnb, 512, owT, 512, 512, ob, nullptr, nullptr, nullptr, (float*)d_out, 0);
}